// Round 16
// baseline (208.569 us; speedup 1.0000x reference)
//
#include <hip/hip_runtime.h>

typedef unsigned short u16;
typedef unsigned int   u32;
typedef _Float16 f16;
typedef f16   f16x8 __attribute__((ext_vector_type(8)));
typedef float f32x4 __attribute__((ext_vector_type(4)));
typedef u16   u16x8 __attribute__((ext_vector_type(8)));
typedef u16   u16x4 __attribute__((ext_vector_type(4)));
typedef u32   u32x4 __attribute__((ext_vector_type(4)));

#define DI __device__ __forceinline__

DI u16  f2h(float f){ f16 h = (f16)f; return __builtin_bit_cast(u16, h); }
DI float h2f(u16 u){ return (float)__builtin_bit_cast(f16, u); }
DI float hlo(u32 u){ return (float)__builtin_bit_cast(f16, (u16)(u & 0xFFFFu)); }
DI float hhi(u32 u){ return (float)__builtin_bit_cast(f16, (u16)(u >> 16)); }

DI f32x4 MFMA(f16x8 a, f16x8 b, f32x4 c){
  return __builtin_amdgcn_mfma_f32_16x16x32_f16(a, b, c, 0, 0, 0);
}

DI u32 pk2(float lo, float hi){
  typedef __fp16 hf16x2 __attribute__((ext_vector_type(2)));
  hf16x2 r = __builtin_amdgcn_cvt_pkrtz(lo, hi);
  return __builtin_bit_cast(u32, r);
}

DI float dot8h(uint4 a, uint4 b){
  float s;
  s  = hlo(a.x)*hlo(b.x) + hhi(a.x)*hhi(b.x);
  s += hlo(a.y)*hlo(b.y) + hhi(a.y)*hhi(b.y);
  s += hlo(a.z)*hlo(b.z) + hhi(a.z)*hhi(b.z);
  s += hlo(a.w)*hlo(b.w) + hhi(a.w)*hhi(b.w);
  return s;
}

// ---------------- workspace layout (bytes) ----------------
constexpr size_t O_XB    = 0;                      // x in f16            16 MB
constexpr size_t O_F1    = O_XB    + 16777216;     // feat1 f16            4 MB
constexpr size_t O_F2H   = O_F1    + 4194304;      // feat2 f16            4 MB (region 8MB)
constexpr size_t O_F2TH  = O_F2H   + 8388608;      // feat2^T f16 [4][128][4096]  4 MB
constexpr size_t O_ENP   = O_F2TH  + 4194304;      // energy partials f32 4 MB
constexpr size_t O_Q     = O_ENP   + 4194304;      // q  f16 [4][4096][32] 1 MB
constexpr size_t O_K     = O_Q     + 1048576;      // k  f16 1 MB
constexpr size_t O_VT    = O_K     + 1048576;      // v^T f16 4 MB
constexpr size_t O_PAM   = O_VT    + 4194304;      // pam f16 4 MB
constexpr size_t O_CAM   = O_PAM   + 4194304;      // cam f16 4 MB
constexpr size_t O_EN    = O_CAM   + 4194304;      // 256KB
constexpr size_t O_ATTC  = O_EN    + 262144;       // attc f16 (region 256KB)
constexpr size_t O_W5AT  = O_ATTC  + 262144;       // w5a folded f16 [9][128][512]
constexpr size_t O_W5CT  = O_W5AT  + 1179648;
constexpr size_t O_W51T  = O_W5CT  + 1179648;      // [9][128][128]
constexpr size_t O_W52T  = O_W51T  + 294912;
constexpr size_t O_WQT   = O_W52T  + 294912;       // [16][128] f16
constexpr size_t O_WKT   = O_WQT   + 4096;
constexpr size_t O_WVT   = O_WKT   + 4096;         // [128][128] f16
constexpr size_t O_W8T   = O_WVT   + 32768;        // [19][128] f16 (padded)
constexpr size_t O_B1    = O_W8T   + 8192;
constexpr size_t O_B2    = O_B1    + 512;
constexpr size_t O_B3    = O_B2    + 512;
constexpr size_t O_B4    = O_B3    + 512;
constexpr size_t O_SA    = O_XB;                   // alias: xb dead after feat convs
constexpr size_t O_SC    = O_XB    + 4194304;
// pam split-K partials (aliases into dead regions):
constexpr size_t O_OP    = O_XB;
constexpr size_t O_ML    = O_F2TH;
constexpr size_t OP_SPLIT_STRIDE = 2097152;        // u16 elems per split (4MB)
constexpr size_t ML_SPLIT_STRIDE = 32768;          // f32 elems per split (128KB)

// ---------------- fused prep (cvt + all weight folds) ----------------
DI void prep_w3_dev(int idx, const float* __restrict__ w, const float* __restrict__ g,
                    const float* __restrict__ bb, const float* __restrict__ m,
                    const float* __restrict__ v, u16* __restrict__ wT,
                    float* __restrict__ bias, int CIN, int lg2){
  const int n = idx & 127;
  const int rest = idx >> 7;
  const int c = rest & (CIN-1);
  const int t = rest >> lg2;
  const float s = g[n] * rsqrtf(v[n] + 1e-3f);
  wT[((size_t)(t*128 + n))*CIN + c] = f2h(w[idx] * s);
  if(rest == 0) bias[n] = bb[n] - m[n]*s;
}

DI void prep_wt_dev(int idx, const float* __restrict__ w, u16* __restrict__ wt, int K, int N){
  if(idx >= K*N) return;
  const int n = idx % N, k = idx / N;
  wt[n*K + k] = f2h(w[idx]);
}

__global__ void prep_all_k(
    const float* __restrict__ x, u16* __restrict__ xh,
    const float* w5a, const float* g1, const float* b1, const float* m1, const float* v1, u16* W5AT, float* B1,
    const float* w5c, const float* g2, const float* b2, const float* m2, const float* v2, u16* W5CT, float* B2,
    const float* w51, const float* g3, const float* b3, const float* m3, const float* v3, u16* W51T, float* B3,
    const float* w52, const float* g4, const float* b4, const float* m4, const float* v4, u16* W52T, float* B4,
    const float* wq, u16* WQT, const float* wk, u16* WKT,
    const float* wv, u16* WVT, const float* w8, u16* W8T)
{
  int bx = blockIdx.x;
  const int t = threadIdx.x;
  if(bx < 8192){
    const int i = (bx*256 + t)*4;
    const float4 v = *(const float4*)(x + i);
    xh[i] = f2h(v.x); xh[i+1] = f2h(v.y); xh[i+2] = f2h(v.z); xh[i+3] = f2h(v.w);
    return;
  }
  bx -= 8192;
  if(bx < 2304){ prep_w3_dev(bx*256+t, w5a, g1,b1,m1,v1, W5AT, B1, 512, 9); return; }
  bx -= 2304;
  if(bx < 2304){ prep_w3_dev(bx*256+t, w5c, g2,b2,m2,v2, W5CT, B2, 512, 9); return; }
  bx -= 2304;
  if(bx < 576){ prep_w3_dev(bx*256+t, w51, g3,b3,m3,v3, W51T, B3, 128, 7); return; }
  bx -= 576;
  if(bx < 576){ prep_w3_dev(bx*256+t, w52, g4,b4,m4,v4, W52T, B4, 128, 7); return; }
  bx -= 576;
  if(bx < 8){ prep_wt_dev(bx*256+t, wq, WQT, 128, 16); return; }
  bx -= 8;
  if(bx < 8){ prep_wt_dev(bx*256+t, wk, WKT, 128, 16); return; }
  bx -= 8;
  if(bx < 64){ prep_wt_dev(bx*256+t, wv, WVT, 128, 128); return; }
  bx -= 64;
  prep_wt_dev(bx*256+t, w8, W8T, 128, 19);
}

// ---------------- conv3x3 v5: pixel-split (64-row tiles, 2 blocks/CU) --------
// r15 analysis: v2 at grid 256 = 1 block/CU was latency-bound (no pipe >35%).
// Split the M dim: 64-row tiles, grid 512 -> 2 co-resident 55KB blocks per CU,
// independent barrier chains interleave. No merge needed (disjoint outputs).
// 8 waves = 2x2 quads (32row x 64col, acc[2][4]) x 2 K-groups; BK=64 dbuf.
template<int CIN>
__global__ __launch_bounds__(512) void conv3x3_k(
    const u16* __restrict__ ina, const u16* __restrict__ wTa,
    const float* __restrict__ ba, u16* oha, u16* otha,
    const u16* __restrict__ inb, const u16* __restrict__ wTb,
    const float* __restrict__ bb, u16* ohb, u16* othb)
{
  __shared__ __align__(16) char SMEM[55296];   // A0@0(9216) A1@9216 B0@18432 B1@36864; epi: 32KB f32

  constexpr int CPS = CIN/64;
  constexpr int S   = 9*CPS;

  const int halfsel = blockIdx.x >> 8;
  const int blk = blockIdx.x & 255;            // 64-row tile index
  const u16* in  = halfsel ? inb : ina;
  const u16* wT  = halfsel ? wTb : wTa;
  const float* bias = halfsel ? bb : ba;
  u16* oh  = halfsel ? ohb : oha;
  u16* oth = halfsel ? othb : otha;

  const int tid = threadIdx.x;
  const int lane = tid & 63;
  const int wid = tid >> 6;
  const int kg = wid >> 2;
  const int wq = wid & 3;
  const int wr = wq >> 1, wc = wq & 1;
  const int l15 = lane & 15;
  const int lg = lane >> 4;
  // A staging: 64 rows x 64ch, 1 u16x8/thread
  const int rowA = tid >> 3;
  const int csA  = (tid & 7) * 8;
  // B staging: 128 rows x 64ch, 2 u16x8/thread
  const int rowB = tid >> 2;
  const int csB  = (tid & 3) * 16;

  const int p = blk*64 + rowA;
  const int b = p >> 12;
  const int rem = p & 4095;
  const int h = rem >> 6, w = rem & 63;

  f32x4 acc[2][4];
  #pragma unroll
  for(int i=0;i<2;++i)
    #pragma unroll
    for(int j=0;j<4;++j){ f32x4 z = {0.f,0.f,0.f,0.f}; acc[i][j] = z; }

  u16x8 ra0, rb0, rb1;
  auto LOAD = [&](int ts){
    const int tap = ts / CPS;
    const int c0 = (ts - tap*CPS)*64;
    const int dy = tap/3 - 1, dx = tap - (tap/3)*3 - 1;
    const int hh = h + dy, ww = w + dx;
    const bool valid = ((unsigned)hh < 64u) && ((unsigned)ww < 64u);
    u16x8 z = {0,0,0,0,0,0,0,0};
    ra0 = z;
    if(valid)
      ra0 = *(const u16x8*)(in + (size_t)((b<<12) + (hh<<6) + ww)*CIN + c0 + csA);
    const u16* bp = wT + (size_t)(tap*128 + rowB)*CIN + c0 + csB;
    rb0 = *(const u16x8*)(bp);
    rb1 = *(const u16x8*)(bp + 8);
  };
  auto STORE = [&](int buf){
    u16* Ad = (u16*)(SMEM + (buf ? 9216 : 0)) + rowA*72 + csA;
    u16* Bd = (u16*)(SMEM + 18432 + (buf ? 18432 : 0)) + rowB*72 + csB;
    *(u16x8*)(Ad)     = ra0;
    *(u16x8*)(Bd)     = rb0;
    *(u16x8*)(Bd + 8) = rb1;
  };

  LOAD(0); STORE(0);
  LOAD(1);
  __syncthreads();

  int cur = 0;
  const int fro = kg*32 + lg*8;
  for(int ts=0; ts<S; ++ts){
    if(ts+1 < S) STORE(cur^1);
    if(ts+2 < S) LOAD(ts+2);
    const u16* Ac = (u16*)(SMEM + (cur ? 9216 : 0));
    const u16* Bc = (u16*)(SMEM + 18432 + (cur ? 18432 : 0));
    f16x8 af[2], bf[4];
    #pragma unroll
    for(int ms=0; ms<2; ++ms)
      af[ms] = *(const f16x8*)(Ac + (wr*32 + ms*16 + l15)*72 + fro);
    #pragma unroll
    for(int ns=0; ns<4; ++ns)
      bf[ns] = *(const f16x8*)(Bc + (wc*64 + ns*16 + l15)*72 + fro);
    #pragma unroll
    for(int ms=0; ms<2; ++ms)
      #pragma unroll
      for(int ns=0; ns<4; ++ns)
        acc[ms][ns] = MFMA(af[ms], bf[ns], acc[ms][ns]);
    __syncthreads();
    cur ^= 1;
  }

  // ---- merge K-groups via LDS (kg1 -> kg0); quad region 32x64 f32 ----
  float* Mg = (float*)SMEM + wq*2048;
  if(kg){
    #pragma unroll
    for(int ms=0; ms<2; ++ms)
      #pragma unroll
      for(int ns=0; ns<4; ++ns)
        #pragma unroll
        for(int r=0; r<4; ++r)
          Mg[(ms*16 + lg*4 + r)*64 + ns*16 + l15] = acc[ms][ns][r];
  }
  __syncthreads();
  if(!kg){
    const int orow0 = blk*64 + wr*32;
    #pragma unroll
    for(int ns=0; ns<4; ++ns){
      const int col = wc*64 + ns*16 + l15;
      const float bc = bias[col];
      #pragma unroll
      for(int ms=0; ms<2; ++ms){
        const int pr0 = orow0 + ms*16 + lg*4;
        float4 vv;
        vv.x = acc[ms][ns][0] + Mg[(ms*16+lg*4+0)*64 + ns*16+l15] + bc; vv.x = vv.x > 0.f ? vv.x : 0.f;
        vv.y = acc[ms][ns][1] + Mg[(ms*16+lg*4+1)*64 + ns*16+l15] + bc; vv.y = vv.y > 0.f ? vv.y : 0.f;
        vv.z = acc[ms][ns][2] + Mg[(ms*16+lg*4+2)*64 + ns*16+l15] + bc; vv.z = vv.z > 0.f ? vv.z : 0.f;
        vv.w = acc[ms][ns][3] + Mg[(ms*16+lg*4+3)*64 + ns*16+l15] + bc; vv.w = vv.w > 0.f ? vv.w : 0.f;
        const u16 h0 = f2h(vv.x), h1 = f2h(vv.y), h2 = f2h(vv.z), h3 = f2h(vv.w);
        if(oh){
          oh[(size_t)(pr0+0)*128 + col] = h0;
          oh[(size_t)(pr0+1)*128 + col] = h1;
          oh[(size_t)(pr0+2)*128 + col] = h2;
          oh[(size_t)(pr0+3)*128 + col] = h3;
        }
        if(oth){
          const int bb2 = pr0 >> 12, pp0 = pr0 & 4095;
          u16x4 hv = {h0, h1, h2, h3};
          *(u16x4*)(oth + (size_t)(bb2*128 + col)*4096 + pp0) = hv;
        }
      }
    }
  }
}

// ------------- mid-stage fused: energy (64) | v_proj (128) | qk_proj (1024) --
__global__ __launch_bounds__(256) void mid_fused_k(
    const u16* __restrict__ f2T, float* __restrict__ enp,
    const u16* __restrict__ feat, const u16* __restrict__ wvt,
    const float* __restrict__ biasv, u16* __restrict__ vT,
    const u16* __restrict__ wtq, const float* __restrict__ biasq,
    const u16* __restrict__ wtk, const float* __restrict__ biask,
    u16* __restrict__ outq, u16* __restrict__ outk)
{
  __shared__ __align__(16) char LDS[34816];
  int bx = blockIdx.x;
  const int tid = threadIdx.x;
  const int lane = tid & 63;
  const int wid = tid >> 6;
  const int wr = wid >> 1, wc = wid & 1;
  const int l15 = lane & 15;
  const int lg = lane >> 4;

  if(bx < 64){
    u16* Xl = (u16*)LDS;
    const int b = bx >> 4, s = bx & 15;
    const int rowS = tid >> 1, half = tid & 1;
    const u16* src = f2T + (size_t)(b*128 + rowS)*4096 + s*256;

    f32x4 acc[4][4];
    #pragma unroll
    for(int i=0;i<4;++i)
      #pragma unroll
      for(int j=0;j<4;++j){ f32x4 z = {0.f,0.f,0.f,0.f}; acc[i][j] = z; }

    for(int it=0; it<4; ++it){
      __syncthreads();
      const u16* sp = src + it*64 + half*32;
      const u16x8 v0 = *(const u16x8*)(sp);
      const u16x8 v1 = *(const u16x8*)(sp + 8);
      const u16x8 v2 = *(const u16x8*)(sp + 16);
      const u16x8 v3 = *(const u16x8*)(sp + 24);
      u16* dl = Xl + rowS*72 + half*32;
      *(u16x8*)(dl)      = v0;
      *(u16x8*)(dl + 8)  = v1;
      *(u16x8*)(dl + 16) = v2;
      *(u16x8*)(dl + 24) = v3;
      __syncthreads();
      #pragma unroll
      for(int kk=0; kk<2; ++kk){
        f16x8 af[4], bf[4];
        #pragma unroll
        for(int ms=0; ms<4; ++ms)
          af[ms] = *(const f16x8*)(Xl + (wr*64 + ms*16 + l15)*72 + kk*32 + lg*8);
        #pragma unroll
        for(int ns=0; ns<4; ++ns)
          bf[ns] = *(const f16x8*)(Xl + (wc*64 + ns*16 + l15)*72 + kk*32 + lg*8);
        #pragma unroll
        for(int ms=0; ms<4; ++ms)
          #pragma unroll
          for(int ns=0; ns<4; ++ns)
            acc[ms][ns] = MFMA(af[ms], bf[ns], acc[ms][ns]);
      }
    }
    float* dst = enp + (size_t)(s*4 + b)*128*128;
    #pragma unroll
    for(int ms=0; ms<4; ++ms){
      const int r0 = wr*64 + ms*16 + lg*4;
      #pragma unroll
      for(int ns=0; ns<4; ++ns){
        const int col = wc*64 + ns*16 + l15;
        #pragma unroll
        for(int r=0; r<4; ++r)
          dst[(size_t)(r0 + r)*128 + col] = acc[ms][ns][r];
      }
    }
    return;
  }
  bx -= 64;
  if(bx < 128){
    u16* Ct = (u16*)LDS;
    const int b = bx >> 5, pb = bx & 31;
    const int p0 = pb*128;

    f32x4 acc[4][4];
    #pragma unroll
    for(int i=0;i<4;++i)
      #pragma unroll
      for(int j=0;j<4;++j){ f32x4 z = {0.f,0.f,0.f,0.f}; acc[i][j] = z; }

    #pragma unroll
    for(int k0=0; k0<128; k0+=32){
      f16x8 af[4], bf[4];
      #pragma unroll
      for(int ms=0; ms<4; ++ms)
        af[ms] = *(const f16x8*)(wvt + (size_t)(wr*64 + ms*16 + l15)*128 + k0 + lg*8);
      #pragma unroll
      for(int ns=0; ns<4; ++ns)
        bf[ns] = *(const f16x8*)(feat + (size_t)(b*4096 + p0 + wc*64 + ns*16 + l15)*128 + k0 + lg*8);
      #pragma unroll
      for(int ms=0; ms<4; ++ms)
        #pragma unroll
        for(int ns=0; ns<4; ++ns)
          acc[ms][ns] = MFMA(af[ms], bf[ns], acc[ms][ns]);
    }
    #pragma unroll
    for(int ms=0; ms<4; ++ms){
      const int n0 = wr*64 + ms*16 + lg*4;
      #pragma unroll
      for(int r=0; r<4; ++r){
        const float bc = biasv[n0 + r];
        #pragma unroll
        for(int ns=0; ns<4; ++ns)
          Ct[(n0+r)*136 + wc*64 + ns*16 + l15] = f2h(acc[ms][ns][r] + bc);
      }
    }
    __syncthreads();
    const int row = tid >> 1, half = tid & 1;
    u16* dst = vT + (size_t)(b*128 + row)*4096 + p0 + half*64;
    const u16* src = Ct + row*136 + half*64;
    #pragma unroll
    for(int j=0; j<8; ++j)
      *(u16x8*)(dst + j*8) = *(const u16x8*)(src + j*8);
    return;
  }
  bx -= 128;
  const int idx = bx*256 + tid;
  const int n = idx & 15, p = idx >> 4;
  const u16* fr = feat + (size_t)p*128;
  const u16* wrq = wtq + n*128;
  const u16* wrk = wtk + n*128;
  float accq = biasq[n], acck = biask[n];
  #pragma unroll
  for(int k=0; k<128; k+=8){
    const uint4 f = *(const uint4*)(fr+k);
    accq += dot8h(f, *(const uint4*)(wrq+k));
    acck += dot8h(f, *(const uint4*)(wrk+k));
  }
  outq[(size_t)p*32 + n] = f2h(accq);
  outq[(size_t)p*32 + 16 + n] = 0;
  outk[(size_t)p*32 + n] = f2h(acck);
  outk[(size_t)p*32 + 16 + n] = 0;
}

// ---------------- PAM flash attention v4 (swapped-S^T, packed-P via LDS) ----
__global__ __launch_bounds__(512) void pam_part_k(
    const u16* __restrict__ q, const u16* __restrict__ km,
    const u16* __restrict__ vT,
    u16* __restrict__ OP, float* __restrict__ ML)
{
  __shared__ u16 Vl[128*136];      // [ch][key] stride 136
  __shared__ u16 Kl[128*40];       // [key][32] stride 40
  __shared__ u32 Pp[8*16*66];      // per-wave packed P: [16 q][66 words]

  const int tid = threadIdx.x;
  const int lane = tid & 63;
  const int wv = tid >> 6;
  const int l15 = lane & 15;
  const int lg = lane >> 4;
  const int koff = lg*8;
  const int qt = blockIdx.x;
  const int b = blockIdx.y;
  const int ks = blockIdx.z;
  const int q0 = qt*256;

  u32* Pw = Pp + wv*16*66;

  const int row4 = tid >> 2, seg = tid & 3;
  const u16* vsrc = vT + (size_t)(b*128 + row4)*4096 + ks*1024 + seg*32;
  const u16* ksrc = km + (size_t)(b*4096 + ks*1024 + row4)*32 + seg*8;
  u16* vdst = Vl + row4*136 + seg*32;
  u16* kdst = Kl + row4*40 + seg*8;

  f16x8 aQ[2];
  #pragma unroll
  for(int f=0; f<2; ++f)
    aQ[f] = *(const f16x8*)(q + (size_t)(b*4096 + q0 + wv*32 + f*16 + l15)*32 + koff);

  float m_r[2] = {-1e30f, -1e30f};
  float l_r[2] = {0.f, 0.f};

  f32x4 accO[8][2];
  #pragma unroll
  for(int i=0;i<8;++i)
    #pragma unroll
    for(int f=0;f<2;++f){ f32x4 z = {0.f,0.f,0.f,0.f}; accO[i][f] = z; }

  u16x8 rv[4], rk;
  #pragma unroll
  for(int j=0;j<4;++j) rv[j] = *(const u16x8*)(vsrc + j*8);
  rk = *(const u16x8*)(ksrc);
  #pragma unroll
  for(int j=0;j<4;++j) *(u16x8*)(vdst + j*8) = rv[j];
  *(u16x8*)(kdst) = rk;
  __syncthreads();

  const int NT = 8;
  for(int t=0; t<NT; ++t){
    if(t+1 < NT){
      vsrc += 128; ksrc += 128*32;
      #pragma unroll
      for(int j=0;j<4;++j) rv[j] = *(const u16x8*)(vsrc + j*8);
      rk = *(const u16x8*)(ksrc);
    }
    f32x4 accST[8][2];
    #pragma unroll
    for(int ns=0; ns<8; ++ns){
      const f16x8 aK = *(const f16x8*)(Kl + (ns*16 + l15)*40 + koff);
      f32x4 z = {0.f,0.f,0.f,0.f};
      accST[ns][0] = MFMA(aK, aQ[0], z);
      accST[ns][1] = MFMA(aK, aQ[1], z);
    }
    float al_[2];
    #pragma unroll
    for(int f=0; f<2; ++f){
      float tmax = accST[0][f][0];
      #pragma unroll
      for(int ns=0; ns<8; ++ns)
        #pragma unroll
        for(int ri=0; ri<4; ++ri) tmax = fmaxf(tmax, accST[ns][f][ri]);
      tmax = fmaxf(tmax, __shfl_xor(tmax, 16));
      tmax = fmaxf(tmax, __shfl_xor(tmax, 32));
      const float mn = fmaxf(m_r[f], tmax);
      const float al = __expf(m_r[f] - mn);
      float ps = 0.f;
      #pragma unroll
      for(int ns=0; ns<8; ++ns)
        #pragma unroll
        for(int ri=0; ri<4; ++ri){
          const float pv = __expf(accST[ns][f][ri] - mn);
          accST[ns][f][ri] = pv;
          ps += pv;
        }
      ps += __shfl_xor(ps, 16);
      ps += __shfl_xor(ps, 32);
      l_r[f] = l_r[f]*al + ps;
      m_r[f] = mn;
      al_[f] = al;
    }
    #pragma unroll
    for(int ns2=0; ns2<8; ++ns2)
      #pragma unroll
      for(int f=0; f<2; ++f)
        #pragma unroll
        for(int ri=0; ri<4; ++ri)
          accO[ns2][f][ri] *= al_[f];
    #pragma unroll
    for(int f=0; f<2; ++f){
      #pragma unroll
      for(int ns=0; ns<8; ++ns){
        uint2 pr;
        pr.x = pk2(accST[ns][f][0], accST[ns][f][1]);
        pr.y = pk2(accST[ns][f][2], accST[ns][f][3]);
        *(uint2*)(Pw + l15*66 + ns*8 + lg*2) = pr;
      }
      #pragma unroll
      for(int kk=0; kk<4; ++kk){
        const uint2 ra = *(const uint2*)(Pw + l15*66 + kk*16 + lg*4);
        const uint2 rb = *(const uint2*)(Pw + l15*66 + kk*16 + lg*4 + 2);
        u32x4 rr; rr.x = ra.x; rr.y = ra.y; rr.z = rb.x; rr.w = rb.y;
        const f16x8 bP = __builtin_bit_cast(f16x8, rr);
        #pragma unroll
        for(int ns2=0; ns2<8; ++ns2){
          const f16x8 av = *(const f16x8*)(Vl + (ns2*16 + l15)*136 + kk*32 + koff);
          accO[ns2][f] = MFMA(av, bP, accO[ns2][f]);
        }
      }
    }
    __syncthreads();
    if(t+1 < NT){
      #pragma unroll
      for(int j=0;j<4;++j) *(u16x8*)(vdst + j*8) = rv[j];
      *(u16x8*)(kdst) = rk;
      __syncthreads();
    }
  }

  u32* op32 = (u32*)(OP + (size_t)ks*OP_SPLIT_STRIDE + (size_t)(b*16 + qt)*32768);
  #pragma unroll
  for(int f=0; f<2; ++f){
    const int ql = wv*32 + f*16 + l15;
    #pragma unroll
    for(int ns2=0; ns2<8; ++ns2)
      #pragma unroll
      for(int h=0; h<2; ++h)
        op32[ql*64 + ns2*8 + lg*2 + h] = pk2(accO[ns2][f][2*h], accO[ns2][f][2*h+1]);
  }
  float* ml = ML + (size_t)ks*ML_SPLIT_STRIDE + (size_t)(b*16 + qt)*512;
  if(lg == 0){
    #pragma unroll
    for(int f=0; f<2; ++f){
      const int ql = wv*32 + f*16 + l15;
      ml[ql*2]     = m_r[f];
      ml[ql*2 + 1] = l_r[f];
    }
  }
}

__global__ void pam_merge_k(const u16* __restrict__ OP, const float* __restrict__ ML,
                            const u16* __restrict__ feat1, const float* __restrict__ gpam,
                            u16* __restrict__ pam)
{
  const int idx = blockIdx.x*256 + threadIdx.x;
  const int ch = idx & 127, qg = idx >> 7;
  const int b = qg >> 12, qq = qg & 4095;
  const int qt = qq >> 8, ql = qq & 255;
  const size_t off = ((size_t)(b*16 + qt)*256 + ql)*128 + ch;
  const size_t mloff = (size_t)(b*16 + qt)*512 + ql*2;
  float m[4], l[4];
  #pragma unroll
  for(int s=0; s<4; ++s){
    m[s] = ML[s*ML_SPLIT_STRIDE + mloff];
    l[s] = ML[s*ML_SPLIT_STRIDE + mloff + 1];
  }
  const float M = fmaxf(fmaxf(m[0],m[1]), fmaxf(m[2],m[3]));
  float num = 0.f, den = 0.f;
  #pragma unroll
  for(int s=0; s<4; ++s){
    const float wgt = __expf(m[s] - M);
    num += wgt * h2f(OP[s*OP_SPLIT_STRIDE + off]);
    den += wgt * l[s];
  }
  pam[idx] = f2h(gpam[0]*num/den + h2f(feat1[idx]));
}

// ---------------- CAM branch (attc + cam) ----------------
__global__ __launch_bounds__(256) void attc_k(const float* __restrict__ enp, u16* __restrict__ attch){
  const int row = blockIdx.x*4 + (threadIdx.x >> 6);
  const int lane = threadIdx.x & 63;
  float e0 = 0.f, e1 = 0.f;
  const int b = row >> 7, c = row & 127;
  #pragma unroll
  for(int s=0; s<16; ++s){
    const float* base = enp + (size_t)(s*4 + b)*128*128 + (size_t)c*128;
    e0 += base[lane];
    e1 += base[64 + lane];
  }
  float mn = fminf(e0, e1);
  #pragma unroll
  for(int d2=1; d2<64; d2<<=1) mn = fminf(mn, __shfl_xor(mn, d2));
  const float p0 = __expf(mn - e0), p1 = __expf(mn - e1);
  float s = p0 + p1;
  #pragma unroll
  for(int d2=1; d2<64; d2<<=1) s += __shfl_xor(s, d2);
  const float rs = 1.f / s;
  attch[(size_t)row*128 + lane]      = f2h(p0*rs);
  attch[(size_t)row*128 + 64 + lane] = f2h(p1*rs);
}

__global__ __launch_bounds__(256) void cam_mfma_k(
    const u16* __restrict__ f2, const u16* __restrict__ attch,
    const float* __restrict__ gcam, u16* __restrict__ cam)
{
  const int b = blockIdx.x >> 5, pt = blockIdx.x & 31;
  const int tid = threadIdx.x;
  const int lane = tid & 63;
  const int wid = tid >> 6;
  const int wr = wid >> 1, wc = wid & 1;
  const int l15 = lane & 15;
  const int lg = lane >> 4;

  f32x4 acc[4][4];
  #pragma unroll
  for(int i=0;i<4;++i)
    #pragma unroll
    for(int j=0;j<4;++j){ f32x4 z = {0.f,0.f,0.f,0.f}; acc[i][j] = z; }

  #pragma unroll
  for(int k0=0; k0<128; k0+=32){
    f16x8 af[4], bf[4];
    #pragma unroll
    for(int ms=0; ms<4; ++ms)
      af[ms] = *(const f16x8*)(f2 + (size_t)(b*4096 + pt*128 + wr*64 + ms*16 + l15)*128 + k0 + lg*8);
    #pragma unroll
    for(int ns=0; ns<4; ++ns)
      bf[ns] = *(const f16x8*)(attch + (size_t)(b*128 + wc*64 + ns*16 + l15)*128 + k0 + lg*8);
    #pragma unroll
    for(int ms=0; ms<4; ++ms)
      #pragma unroll
      for(int ns=0; ns<4; ++ns)
        acc[ms][ns] = MFMA(af[ms], bf[ns], acc[ms][ns]);
  }
  const float g = gcam[0];
  #pragma unroll
  for(int ms=0; ms<4; ++ms)
    #pragma unroll
    for(int ns=0; ns<4; ++ns){
      const int col = wc*64 + ns*16 + l15;
      #pragma unroll
      for(int r=0; r<4; ++r){
        const int p = pt*128 + wr*64 + ms*16 + lg*4 + r;
        const size_t off = (size_t)(b*4096 + p)*128 + col;
        cam[off] = f2h(g*acc[ms][ns][r] + h2f(f2[off]));
      }
    }
}

// ---------------- fusion conv1x1 -> out ----------------
__global__ void final_k(const u16* __restrict__ sa, const u16* __restrict__ sc,
                        const u16* __restrict__ w8t, float* __restrict__ out){
  const int idx = blockIdx.x*256 + threadIdx.x;
  if(idx >= 16384*19) return;
  const int p = idx / 19, n = idx - p*19;
  const u16* ra = sa + (size_t)p*128;
  const u16* rb = sc + (size_t)p*128;
  const u16* wr = w8t + (size_t)n*128;
  float acc = 0.f;
  #pragma unroll
  for(int k=0; k<128; k+=8){
    const uint4 a = *(const uint4*)(ra+k);
    const uint4 b = *(const uint4*)(rb+k);
    const uint4 w = *(const uint4*)(wr+k);
    acc += (hlo(a.x)+hlo(b.x))*hlo(w.x) + (hhi(a.x)+hhi(b.x))*hhi(w.x);
    acc += (hlo(a.y)+hlo(b.y))*hlo(w.y) + (hhi(a.y)+hhi(b.y))*hhi(w.y);
    acc += (hlo(a.z)+hlo(b.z))*hlo(w.z) + (hhi(a.z)+hhi(b.z))*hhi(w.z);
    acc += (hlo(a.w)+hlo(b.w))*hlo(w.w) + (hhi(a.w)+hhi(b.w))*hhi(w.w);
  }
  out[idx] = acc;
}

// ---------------- launch ----------------
extern "C" void kernel_launch(void* const* d_in, const int* in_sizes, int n_in,
                              void* d_out, int out_size, void* d_ws, size_t ws_size,
                              hipStream_t stream)
{
  const float* x    = (const float*)d_in[0];
  const float* w5a  = (const float*)d_in[1];
  const float* bn1g = (const float*)d_in[2];
  const float* bn1b = (const float*)d_in[3];
  const float* bn1m = (const float*)d_in[4];
  const float* bn1v = (const float*)d_in[5];
  const float* wq   = (const float*)d_in[6];
  const float* bq   = (const float*)d_in[7];
  const float* wk   = (const float*)d_in[8];
  const float* bk   = (const float*)d_in[9];
  const float* wv   = (const float*)d_in[10];
  const float* bv   = (const float*)d_in[11];
  const float* gpam = (const float*)d_in[12];
  const float* w5c  = (const float*)d_in[13];
  const float* bn2g = (const float*)d_in[14];
  const float* bn2b = (const float*)d_in[15];
  const float* bn2m = (const float*)d_in[16];
  const float* bn2v = (const float*)d_in[17];
  const float* gcam = (const float*)d_in[18];
  const float* w51  = (const float*)d_in[19];
  const float* bn3g = (const float*)d_in[20];
  const float* bn3b = (const float*)d_in[21];
  const float* bn3m = (const float*)d_in[22];
  const float* bn3v = (const float*)d_in[23];
  const float* w52  = (const float*)d_in[24];
  const float* bn4g = (const float*)d_in[25];
  const float* bn4b = (const float*)d_in[26];
  const float* bn4m = (const float*)d_in[27];
  const float* bn4v = (const float*)d_in[28];
  const float* w8   = (const float*)d_in[29];

  char* ws = (char*)d_ws;
  u16*   XB    = (u16*)(ws + O_XB);
  u16*   FEAT1 = (u16*)(ws + O_F1);
  u16*   F2H   = (u16*)(ws + O_F2H);
  u16*   F2TH  = (u16*)(ws + O_F2TH);
  float* ENP   = (float*)(ws + O_ENP);
  u16*   Q     = (u16*)(ws + O_Q);
  u16*   KM    = (u16*)(ws + O_K);
  u16*   VT    = (u16*)(ws + O_VT);
  u16*   PAM   = (u16*)(ws + O_PAM);
  u16*   CAM   = (u16*)(ws + O_CAM);
  u16*   ATTCH = (u16*)(ws + O_ATTC);
  u16*   OP    = (u16*)(ws + O_OP);
  float* ML    = (float*)(ws + O_ML);
  u16*   W5AT  = (u16*)(ws + O_W5AT);
  u16*   W5CT  = (u16*)(ws + O_W5CT);
  u16*   W51T  = (u16*)(ws + O_W51T);
  u16*   W52T  = (u16*)(ws + O_W52T);
  u16*   WQT   = (u16*)(ws + O_WQT);
  u16*   WKT   = (u16*)(ws + O_WKT);
  u16*   WVT   = (u16*)(ws + O_WVT);
  u16*   W8T   = (u16*)(ws + O_W8T);
  float* B1    = (float*)(ws + O_B1);
  float* B2    = (float*)(ws + O_B2);
  float* B3    = (float*)(ws + O_B3);
  float* B4    = (float*)(ws + O_B4);
  u16*   SA    = (u16*)(ws + O_SA);
  u16*   SC    = (u16*)(ws + O_SC);
  float* OUT   = (float*)d_out;

  prep_all_k<<<14042,256,0,stream>>>(x, XB,
      w5a, bn1g,bn1b,bn1m,bn1v, W5AT, B1,
      w5c, bn2g,bn2b,bn2m,bn2v, W5CT, B2,
      w51, bn3g,bn3b,bn3m,bn3v, W51T, B3,
      w52, bn4g,bn4b,bn4m,bn4v, W52T, B4,
      wq, WQT, wk, WKT, wv, WVT, w8, W8T);

  // feat1 (f16) and feat2 (f16 row-major + f16 transposed), 64-row tiles
  conv3x3_k<512><<<512,512,0,stream>>>(XB, W5AT, B1, FEAT1, nullptr,
                                       XB, W5CT, B2, F2H, F2TH);

  // energy | v_proj | qk_proj fused (all depend only on conv1 outputs)
  mid_fused_k<<<1216,256,0,stream>>>(F2TH, ENP,
                                     FEAT1, WVT, bv, VT,
                                     WQT, bq, WKT, bk, Q, KM);

  attc_k<<<128,256,0,stream>>>(ENP, ATTCH);
  cam_mfma_k<<<128,256,0,stream>>>(F2H, ATTCH, gcam, CAM);

  // PAM: 4-way split-K flash v4 + merge (OP in dead XB region)
  pam_part_k<<<dim3(16,4,4),512,0,stream>>>(Q, KM, VT, OP, ML);
  pam_merge_k<<<8192,256,0,stream>>>(OP, ML, FEAT1, gpam, PAM);

  // sa_conv (from pam) and sc_conv (from cam); SA/SC alias XB
  conv3x3_k<128><<<512,512,0,stream>>>(PAM, W51T, B3, SA, nullptr,
                                       CAM, W52T, B4, SC, nullptr);

  final_k<<<1216,256,0,stream>>>(SA, SC, W8T, OUT);
}

// Round 17
// 202.695 us; speedup vs baseline: 1.0290x; 1.0290x over previous
//
#include <hip/hip_runtime.h>

typedef unsigned short u16;
typedef unsigned int   u32;
typedef _Float16 f16;
typedef f16   f16x8 __attribute__((ext_vector_type(8)));
typedef float f32x4 __attribute__((ext_vector_type(4)));
typedef u16   u16x8 __attribute__((ext_vector_type(8)));
typedef u16   u16x4 __attribute__((ext_vector_type(4)));
typedef u32   u32x4 __attribute__((ext_vector_type(4)));

#define DI __device__ __forceinline__

DI u16  f2h(float f){ f16 h = (f16)f; return __builtin_bit_cast(u16, h); }
DI float h2f(u16 u){ return (float)__builtin_bit_cast(f16, u); }
DI float hlo(u32 u){ return (float)__builtin_bit_cast(f16, (u16)(u & 0xFFFFu)); }
DI float hhi(u32 u){ return (float)__builtin_bit_cast(f16, (u16)(u >> 16)); }

DI f32x4 MFMA(f16x8 a, f16x8 b, f32x4 c){
  return __builtin_amdgcn_mfma_f32_16x16x32_f16(a, b, c, 0, 0, 0);
}

DI u32 pk2(float lo, float hi){
  typedef __fp16 hf16x2 __attribute__((ext_vector_type(2)));
  hf16x2 r = __builtin_amdgcn_cvt_pkrtz(lo, hi);
  return __builtin_bit_cast(u32, r);
}

DI float dot8h(uint4 a, uint4 b){
  float s;
  s  = hlo(a.x)*hlo(b.x) + hhi(a.x)*hhi(b.x);
  s += hlo(a.y)*hlo(b.y) + hhi(a.y)*hhi(b.y);
  s += hlo(a.z)*hlo(b.z) + hhi(a.z)*hhi(b.z);
  s += hlo(a.w)*hlo(b.w) + hhi(a.w)*hhi(b.w);
  return s;
}

// ---------------- workspace layout (bytes) ----------------
constexpr size_t O_XB    = 0;                      // x in f16            16 MB
constexpr size_t O_F1    = O_XB    + 16777216;     // feat1 f16            4 MB
constexpr size_t O_F2H   = O_F1    + 4194304;      // feat2 f16            4 MB (region 8MB)
constexpr size_t O_F2TH  = O_F2H   + 8388608;      // feat2^T f16 [4][128][4096]  4 MB
constexpr size_t O_ENP   = O_F2TH  + 4194304;      // energy partials f32 4 MB
constexpr size_t O_Q     = O_ENP   + 4194304;      // q  f16 [4][4096][32] 1 MB
constexpr size_t O_K     = O_Q     + 1048576;      // k  f16 1 MB
constexpr size_t O_VT    = O_K     + 1048576;      // v^T f16 4 MB
constexpr size_t O_PAM   = O_VT    + 4194304;      // pam f16 4 MB
constexpr size_t O_CAM   = O_PAM   + 4194304;      // cam f16 4 MB
constexpr size_t O_EN    = O_CAM   + 4194304;      // 256KB
constexpr size_t O_ATTC  = O_EN    + 262144;       // attc f16 (region 256KB)
constexpr size_t O_W5AT  = O_ATTC  + 262144;       // w5a folded f16 [9][128][512]
constexpr size_t O_W5CT  = O_W5AT  + 1179648;
constexpr size_t O_W51T  = O_W5CT  + 1179648;      // [9][128][128]
constexpr size_t O_W52T  = O_W51T  + 294912;
constexpr size_t O_WQT   = O_W52T  + 294912;       // [16][128] f16
constexpr size_t O_WKT   = O_WQT   + 4096;
constexpr size_t O_WVT   = O_WKT   + 4096;         // [128][128] f16
constexpr size_t O_W8T   = O_WVT   + 32768;        // [19][128] f16 (padded)
constexpr size_t O_B1    = O_W8T   + 8192;
constexpr size_t O_B2    = O_B1    + 512;
constexpr size_t O_B3    = O_B2    + 512;
constexpr size_t O_B4    = O_B3    + 512;
constexpr size_t O_SA    = O_XB;                   // alias: xb dead after feat convs
constexpr size_t O_SC    = O_XB    + 4194304;
// pam split-K partials (aliases into dead regions):
constexpr size_t O_OP    = O_XB;
constexpr size_t O_ML    = O_F2TH;
constexpr size_t OP_SPLIT_STRIDE = 2097152;        // u16 elems per split (4MB)
constexpr size_t ML_SPLIT_STRIDE = 32768;          // f32 elems per split (128KB)

// ---------------- fused prep (cvt + all weight folds) ----------------
DI void prep_w3_dev(int idx, const float* __restrict__ w, const float* __restrict__ g,
                    const float* __restrict__ bb, const float* __restrict__ m,
                    const float* __restrict__ v, u16* __restrict__ wT,
                    float* __restrict__ bias, int CIN, int lg2){
  const int n = idx & 127;
  const int rest = idx >> 7;
  const int c = rest & (CIN-1);
  const int t = rest >> lg2;
  const float s = g[n] * rsqrtf(v[n] + 1e-3f);
  wT[((size_t)(t*128 + n))*CIN + c] = f2h(w[idx] * s);
  if(rest == 0) bias[n] = bb[n] - m[n]*s;
}

DI void prep_wt_dev(int idx, const float* __restrict__ w, u16* __restrict__ wt, int K, int N){
  if(idx >= K*N) return;
  const int n = idx % N, k = idx / N;
  wt[n*K + k] = f2h(w[idx]);
}

__global__ void prep_all_k(
    const float* __restrict__ x, u16* __restrict__ xh,
    const float* w5a, const float* g1, const float* b1, const float* m1, const float* v1, u16* W5AT, float* B1,
    const float* w5c, const float* g2, const float* b2, const float* m2, const float* v2, u16* W5CT, float* B2,
    const float* w51, const float* g3, const float* b3, const float* m3, const float* v3, u16* W51T, float* B3,
    const float* w52, const float* g4, const float* b4, const float* m4, const float* v4, u16* W52T, float* B4,
    const float* wq, u16* WQT, const float* wk, u16* WKT,
    const float* wv, u16* WVT, const float* w8, u16* W8T)
{
  int bx = blockIdx.x;
  const int t = threadIdx.x;
  if(bx < 8192){
    const int i = (bx*256 + t)*4;
    const float4 v = *(const float4*)(x + i);
    xh[i] = f2h(v.x); xh[i+1] = f2h(v.y); xh[i+2] = f2h(v.z); xh[i+3] = f2h(v.w);
    return;
  }
  bx -= 8192;
  if(bx < 2304){ prep_w3_dev(bx*256+t, w5a, g1,b1,m1,v1, W5AT, B1, 512, 9); return; }
  bx -= 2304;
  if(bx < 2304){ prep_w3_dev(bx*256+t, w5c, g2,b2,m2,v2, W5CT, B2, 512, 9); return; }
  bx -= 2304;
  if(bx < 576){ prep_w3_dev(bx*256+t, w51, g3,b3,m3,v3, W51T, B3, 128, 7); return; }
  bx -= 576;
  if(bx < 576){ prep_w3_dev(bx*256+t, w52, g4,b4,m4,v4, W52T, B4, 128, 7); return; }
  bx -= 576;
  if(bx < 8){ prep_wt_dev(bx*256+t, wq, WQT, 128, 16); return; }
  bx -= 8;
  if(bx < 8){ prep_wt_dev(bx*256+t, wk, WKT, 128, 16); return; }
  bx -= 8;
  if(bx < 64){ prep_wt_dev(bx*256+t, wv, WVT, 128, 128); return; }
  bx -= 64;
  prep_wt_dev(bx*256+t, w8, W8T, 128, 19);
}

// ---------------- conv3x3 v2 (implicit GEMM, MFMA, fused pair) ----------------
// Final form: 128-row tiles, grid 256, A+B via dbuf LDS, 1 barrier/step,
// 2 K-groups merged via LDS. Structural plateau at ~68us: split-K (r14),
// pixel-split (r16), direct-B (r12) all land 67-111us; this is min-fetch.
template<int CIN>
__global__ __launch_bounds__(512) void conv3x3_k(
    const u16* __restrict__ ina, const u16* __restrict__ wTa,
    const float* __restrict__ ba, u16* oha, u16* otha,
    const u16* __restrict__ inb, const u16* __restrict__ wTb,
    const float* __restrict__ bb, u16* ohb, u16* othb)
{
  __shared__ __align__(16) char SMEM[73728];

  constexpr int CPS = CIN/64;
  constexpr int S   = 9*CPS;

  const int halfsel = blockIdx.x >> 7;
  const int blk = blockIdx.x & 127;
  const u16* in  = halfsel ? inb : ina;
  const u16* wT  = halfsel ? wTb : wTa;
  const float* bias = halfsel ? bb : ba;
  u16* oh  = halfsel ? ohb : oha;
  u16* oth = halfsel ? othb : otha;

  const int tid = threadIdx.x;
  const int lane = tid & 63;
  const int wid = tid >> 6;
  const int kg = wid >> 2;
  const int wq = wid & 3;
  const int wr = wq >> 1, wc = wq & 1;
  const int l15 = lane & 15;
  const int lg = lane >> 4;
  const int rowS = tid >> 2;
  const int cst  = (tid & 3) * 16;

  const int p = blk*128 + rowS;
  const int b = p >> 12;
  const int rem = p & 4095;
  const int h = rem >> 6, w = rem & 63;

  f32x4 acc[4][4];
  #pragma unroll
  for(int i=0;i<4;++i)
    #pragma unroll
    for(int j=0;j<4;++j){ f32x4 z = {0.f,0.f,0.f,0.f}; acc[i][j] = z; }

  u16x8 ra0, ra1, rb0, rb1;
  auto LOAD = [&](int ts){
    const int tap = ts / CPS;
    const int c0 = (ts - tap*CPS)*64;
    const int dy = tap/3 - 1, dx = tap - (tap/3)*3 - 1;
    const int hh = h + dy, ww = w + dx;
    const bool valid = ((unsigned)hh < 64u) && ((unsigned)ww < 64u);
    u16x8 z = {0,0,0,0,0,0,0,0};
    ra0 = z; ra1 = z;
    if(valid){
      const u16* sp = in + (size_t)((b<<12) + (hh<<6) + ww)*CIN + c0 + cst;
      ra0 = *(const u16x8*)(sp);
      ra1 = *(const u16x8*)(sp + 8);
    }
    const u16* bp = wT + (size_t)(tap*128 + rowS)*CIN + c0 + cst;
    rb0 = *(const u16x8*)(bp);
    rb1 = *(const u16x8*)(bp + 8);
  };
  auto STORE = [&](int buf){
    u16* Ad = (u16*)(SMEM + (buf ? 18432 : 0)) + rowS*72 + cst;
    u16* Bd = (u16*)(SMEM + 36864 + (buf ? 18432 : 0)) + rowS*72 + cst;
    *(u16x8*)(Ad)     = ra0;
    *(u16x8*)(Ad + 8) = ra1;
    *(u16x8*)(Bd)     = rb0;
    *(u16x8*)(Bd + 8) = rb1;
  };

  LOAD(0); STORE(0);
  LOAD(1);
  __syncthreads();

  int cur = 0;
  const int fro = kg*32 + lg*8;
  for(int ts=0; ts<S; ++ts){
    if(ts+1 < S) STORE(cur^1);
    if(ts+2 < S) LOAD(ts+2);
    const u16* Ac = (u16*)(SMEM + (cur ? 18432 : 0));
    const u16* Bc = (u16*)(SMEM + 36864 + (cur ? 18432 : 0));
    f16x8 af[4], bf[4];
    #pragma unroll
    for(int ms=0; ms<4; ++ms)
      af[ms] = *(const f16x8*)(Ac + (wr*64 + ms*16 + l15)*72 + fro);
    #pragma unroll
    for(int ns=0; ns<4; ++ns)
      bf[ns] = *(const f16x8*)(Bc + (wc*64 + ns*16 + l15)*72 + fro);
    #pragma unroll
    for(int ms=0; ms<4; ++ms)
      #pragma unroll
      for(int ns=0; ns<4; ++ns)
        acc[ms][ns] = MFMA(af[ms], bf[ns], acc[ms][ns]);
    __syncthreads();
    cur ^= 1;
  }

  // ---- merge K-groups via LDS (kg1 -> kg0) ----
  float* Mg = (float*)SMEM + wq*4096;
  if(kg){
    #pragma unroll
    for(int ms=0; ms<4; ++ms)
      #pragma unroll
      for(int ns=0; ns<4; ++ns)
        #pragma unroll
        for(int r=0; r<4; ++r)
          Mg[(ms*16 + lg*4 + r)*64 + ns*16 + l15] = acc[ms][ns][r];
  }
  __syncthreads();
  if(!kg){
    const int orow0 = blk*128 + wr*64;
    #pragma unroll
    for(int ns=0; ns<4; ++ns){
      const int col = wc*64 + ns*16 + l15;
      const float bc = bias[col];
      #pragma unroll
      for(int ms=0; ms<4; ++ms){
        const int pr0 = orow0 + ms*16 + lg*4;
        float4 vv;
        vv.x = acc[ms][ns][0] + Mg[(ms*16+lg*4+0)*64 + ns*16+l15] + bc; vv.x = vv.x > 0.f ? vv.x : 0.f;
        vv.y = acc[ms][ns][1] + Mg[(ms*16+lg*4+1)*64 + ns*16+l15] + bc; vv.y = vv.y > 0.f ? vv.y : 0.f;
        vv.z = acc[ms][ns][2] + Mg[(ms*16+lg*4+2)*64 + ns*16+l15] + bc; vv.z = vv.z > 0.f ? vv.z : 0.f;
        vv.w = acc[ms][ns][3] + Mg[(ms*16+lg*4+3)*64 + ns*16+l15] + bc; vv.w = vv.w > 0.f ? vv.w : 0.f;
        const u16 h0 = f2h(vv.x), h1 = f2h(vv.y), h2 = f2h(vv.z), h3 = f2h(vv.w);
        if(oh){
          oh[(size_t)(pr0+0)*128 + col] = h0;
          oh[(size_t)(pr0+1)*128 + col] = h1;
          oh[(size_t)(pr0+2)*128 + col] = h2;
          oh[(size_t)(pr0+3)*128 + col] = h3;
        }
        if(oth){
          const int bb2 = pr0 >> 12, pp0 = pr0 & 4095;
          u16x4 hv = {h0, h1, h2, h3};
          *(u16x4*)(oth + (size_t)(bb2*128 + col)*4096 + pp0) = hv;
        }
      }
    }
  }
}

// ------------- mid-stage fused: energy (64) | v_proj (128) | qk_proj (1024) --
__global__ __launch_bounds__(256) void mid_fused_k(
    const u16* __restrict__ f2T, float* __restrict__ enp,
    const u16* __restrict__ feat, const u16* __restrict__ wvt,
    const float* __restrict__ biasv, u16* __restrict__ vT,
    const u16* __restrict__ wtq, const float* __restrict__ biasq,
    const u16* __restrict__ wtk, const float* __restrict__ biask,
    u16* __restrict__ outq, u16* __restrict__ outk)
{
  __shared__ __align__(16) char LDS[34816];
  int bx = blockIdx.x;
  const int tid = threadIdx.x;
  const int lane = tid & 63;
  const int wid = tid >> 6;
  const int wr = wid >> 1, wc = wid & 1;
  const int l15 = lane & 15;
  const int lg = lane >> 4;

  if(bx < 64){
    u16* Xl = (u16*)LDS;
    const int b = bx >> 4, s = bx & 15;
    const int rowS = tid >> 1, half = tid & 1;
    const u16* src = f2T + (size_t)(b*128 + rowS)*4096 + s*256;

    f32x4 acc[4][4];
    #pragma unroll
    for(int i=0;i<4;++i)
      #pragma unroll
      for(int j=0;j<4;++j){ f32x4 z = {0.f,0.f,0.f,0.f}; acc[i][j] = z; }

    for(int it=0; it<4; ++it){
      __syncthreads();
      const u16* sp = src + it*64 + half*32;
      const u16x8 v0 = *(const u16x8*)(sp);
      const u16x8 v1 = *(const u16x8*)(sp + 8);
      const u16x8 v2 = *(const u16x8*)(sp + 16);
      const u16x8 v3 = *(const u16x8*)(sp + 24);
      u16* dl = Xl + rowS*72 + half*32;
      *(u16x8*)(dl)      = v0;
      *(u16x8*)(dl + 8)  = v1;
      *(u16x8*)(dl + 16) = v2;
      *(u16x8*)(dl + 24) = v3;
      __syncthreads();
      #pragma unroll
      for(int kk=0; kk<2; ++kk){
        f16x8 af[4], bf[4];
        #pragma unroll
        for(int ms=0; ms<4; ++ms)
          af[ms] = *(const f16x8*)(Xl + (wr*64 + ms*16 + l15)*72 + kk*32 + lg*8);
        #pragma unroll
        for(int ns=0; ns<4; ++ns)
          bf[ns] = *(const f16x8*)(Xl + (wc*64 + ns*16 + l15)*72 + kk*32 + lg*8);
        #pragma unroll
        for(int ms=0; ms<4; ++ms)
          #pragma unroll
          for(int ns=0; ns<4; ++ns)
            acc[ms][ns] = MFMA(af[ms], bf[ns], acc[ms][ns]);
      }
    }
    float* dst = enp + (size_t)(s*4 + b)*128*128;
    #pragma unroll
    for(int ms=0; ms<4; ++ms){
      const int r0 = wr*64 + ms*16 + lg*4;
      #pragma unroll
      for(int ns=0; ns<4; ++ns){
        const int col = wc*64 + ns*16 + l15;
        #pragma unroll
        for(int r=0; r<4; ++r)
          dst[(size_t)(r0 + r)*128 + col] = acc[ms][ns][r];
      }
    }
    return;
  }
  bx -= 64;
  if(bx < 128){
    u16* Ct = (u16*)LDS;
    const int b = bx >> 5, pb = bx & 31;
    const int p0 = pb*128;

    f32x4 acc[4][4];
    #pragma unroll
    for(int i=0;i<4;++i)
      #pragma unroll
      for(int j=0;j<4;++j){ f32x4 z = {0.f,0.f,0.f,0.f}; acc[i][j] = z; }

    #pragma unroll
    for(int k0=0; k0<128; k0+=32){
      f16x8 af[4], bf[4];
      #pragma unroll
      for(int ms=0; ms<4; ++ms)
        af[ms] = *(const f16x8*)(wvt + (size_t)(wr*64 + ms*16 + l15)*128 + k0 + lg*8);
      #pragma unroll
      for(int ns=0; ns<4; ++ns)
        bf[ns] = *(const f16x8*)(feat + (size_t)(b*4096 + p0 + wc*64 + ns*16 + l15)*128 + k0 + lg*8);
      #pragma unroll
      for(int ms=0; ms<4; ++ms)
        #pragma unroll
        for(int ns=0; ns<4; ++ns)
          acc[ms][ns] = MFMA(af[ms], bf[ns], acc[ms][ns]);
    }
    #pragma unroll
    for(int ms=0; ms<4; ++ms){
      const int n0 = wr*64 + ms*16 + lg*4;
      #pragma unroll
      for(int r=0; r<4; ++r){
        const float bc = biasv[n0 + r];
        #pragma unroll
        for(int ns=0; ns<4; ++ns)
          Ct[(n0+r)*136 + wc*64 + ns*16 + l15] = f2h(acc[ms][ns][r] + bc);
      }
    }
    __syncthreads();
    const int row = tid >> 1, half = tid & 1;
    u16* dst = vT + (size_t)(b*128 + row)*4096 + p0 + half*64;
    const u16* src = Ct + row*136 + half*64;
    #pragma unroll
    for(int j=0; j<8; ++j)
      *(u16x8*)(dst + j*8) = *(const u16x8*)(src + j*8);
    return;
  }
  bx -= 128;
  const int idx = bx*256 + tid;
  const int n = idx & 15, p = idx >> 4;
  const u16* fr = feat + (size_t)p*128;
  const u16* wrq = wtq + n*128;
  const u16* wrk = wtk + n*128;
  float accq = biasq[n], acck = biask[n];
  #pragma unroll
  for(int k=0; k<128; k+=8){
    const uint4 f = *(const uint4*)(fr+k);
    accq += dot8h(f, *(const uint4*)(wrq+k));
    acck += dot8h(f, *(const uint4*)(wrk+k));
  }
  outq[(size_t)p*32 + n] = f2h(accq);
  outq[(size_t)p*32 + 16 + n] = 0;
  outk[(size_t)p*32 + n] = f2h(acck);
  outk[(size_t)p*32 + 16 + n] = 0;
}

// ---------------- PAM flash attention v4 (swapped-S^T, packed-P via LDS) ----
__global__ __launch_bounds__(512) void pam_part_k(
    const u16* __restrict__ q, const u16* __restrict__ km,
    const u16* __restrict__ vT,
    u16* __restrict__ OP, float* __restrict__ ML)
{
  __shared__ u16 Vl[128*136];      // [ch][key] stride 136
  __shared__ u16 Kl[128*40];       // [key][32] stride 40
  __shared__ u32 Pp[8*16*66];      // per-wave packed P: [16 q][66 words]

  const int tid = threadIdx.x;
  const int lane = tid & 63;
  const int wv = tid >> 6;
  const int l15 = lane & 15;
  const int lg = lane >> 4;
  const int koff = lg*8;
  const int qt = blockIdx.x;
  const int b = blockIdx.y;
  const int ks = blockIdx.z;
  const int q0 = qt*256;

  u32* Pw = Pp + wv*16*66;

  const int row4 = tid >> 2, seg = tid & 3;
  const u16* vsrc = vT + (size_t)(b*128 + row4)*4096 + ks*1024 + seg*32;
  const u16* ksrc = km + (size_t)(b*4096 + ks*1024 + row4)*32 + seg*8;
  u16* vdst = Vl + row4*136 + seg*32;
  u16* kdst = Kl + row4*40 + seg*8;

  f16x8 aQ[2];
  #pragma unroll
  for(int f=0; f<2; ++f)
    aQ[f] = *(const f16x8*)(q + (size_t)(b*4096 + q0 + wv*32 + f*16 + l15)*32 + koff);

  float m_r[2] = {-1e30f, -1e30f};
  float l_r[2] = {0.f, 0.f};

  f32x4 accO[8][2];
  #pragma unroll
  for(int i=0;i<8;++i)
    #pragma unroll
    for(int f=0;f<2;++f){ f32x4 z = {0.f,0.f,0.f,0.f}; accO[i][f] = z; }

  u16x8 rv[4], rk;
  #pragma unroll
  for(int j=0;j<4;++j) rv[j] = *(const u16x8*)(vsrc + j*8);
  rk = *(const u16x8*)(ksrc);
  #pragma unroll
  for(int j=0;j<4;++j) *(u16x8*)(vdst + j*8) = rv[j];
  *(u16x8*)(kdst) = rk;
  __syncthreads();

  const int NT = 8;
  for(int t=0; t<NT; ++t){
    if(t+1 < NT){
      vsrc += 128; ksrc += 128*32;
      #pragma unroll
      for(int j=0;j<4;++j) rv[j] = *(const u16x8*)(vsrc + j*8);
      rk = *(const u16x8*)(ksrc);
    }
    f32x4 accST[8][2];
    #pragma unroll
    for(int ns=0; ns<8; ++ns){
      const f16x8 aK = *(const f16x8*)(Kl + (ns*16 + l15)*40 + koff);
      f32x4 z = {0.f,0.f,0.f,0.f};
      accST[ns][0] = MFMA(aK, aQ[0], z);
      accST[ns][1] = MFMA(aK, aQ[1], z);
    }
    float al_[2];
    #pragma unroll
    for(int f=0; f<2; ++f){
      float tmax = accST[0][f][0];
      #pragma unroll
      for(int ns=0; ns<8; ++ns)
        #pragma unroll
        for(int ri=0; ri<4; ++ri) tmax = fmaxf(tmax, accST[ns][f][ri]);
      tmax = fmaxf(tmax, __shfl_xor(tmax, 16));
      tmax = fmaxf(tmax, __shfl_xor(tmax, 32));
      const float mn = fmaxf(m_r[f], tmax);
      const float al = __expf(m_r[f] - mn);
      float ps = 0.f;
      #pragma unroll
      for(int ns=0; ns<8; ++ns)
        #pragma unroll
        for(int ri=0; ri<4; ++ri){
          const float pv = __expf(accST[ns][f][ri] - mn);
          accST[ns][f][ri] = pv;
          ps += pv;
        }
      ps += __shfl_xor(ps, 16);
      ps += __shfl_xor(ps, 32);
      l_r[f] = l_r[f]*al + ps;
      m_r[f] = mn;
      al_[f] = al;
    }
    #pragma unroll
    for(int ns2=0; ns2<8; ++ns2)
      #pragma unroll
      for(int f=0; f<2; ++f)
        #pragma unroll
        for(int ri=0; ri<4; ++ri)
          accO[ns2][f][ri] *= al_[f];
    #pragma unroll
    for(int f=0; f<2; ++f){
      #pragma unroll
      for(int ns=0; ns<8; ++ns){
        uint2 pr;
        pr.x = pk2(accST[ns][f][0], accST[ns][f][1]);
        pr.y = pk2(accST[ns][f][2], accST[ns][f][3]);
        *(uint2*)(Pw + l15*66 + ns*8 + lg*2) = pr;
      }
      #pragma unroll
      for(int kk=0; kk<4; ++kk){
        const uint2 ra = *(const uint2*)(Pw + l15*66 + kk*16 + lg*4);
        const uint2 rb = *(const uint2*)(Pw + l15*66 + kk*16 + lg*4 + 2);
        u32x4 rr; rr.x = ra.x; rr.y = ra.y; rr.z = rb.x; rr.w = rb.y;
        const f16x8 bP = __builtin_bit_cast(f16x8, rr);
        #pragma unroll
        for(int ns2=0; ns2<8; ++ns2){
          const f16x8 av = *(const f16x8*)(Vl + (ns2*16 + l15)*136 + kk*32 + koff);
          accO[ns2][f] = MFMA(av, bP, accO[ns2][f]);
        }
      }
    }
    __syncthreads();
    if(t+1 < NT){
      #pragma unroll
      for(int j=0;j<4;++j) *(u16x8*)(vdst + j*8) = rv[j];
      *(u16x8*)(kdst) = rk;
      __syncthreads();
    }
  }

  u32* op32 = (u32*)(OP + (size_t)ks*OP_SPLIT_STRIDE + (size_t)(b*16 + qt)*32768);
  #pragma unroll
  for(int f=0; f<2; ++f){
    const int ql = wv*32 + f*16 + l15;
    #pragma unroll
    for(int ns2=0; ns2<8; ++ns2)
      #pragma unroll
      for(int h=0; h<2; ++h)
        op32[ql*64 + ns2*8 + lg*2 + h] = pk2(accO[ns2][f][2*h], accO[ns2][f][2*h+1]);
  }
  float* ml = ML + (size_t)ks*ML_SPLIT_STRIDE + (size_t)(b*16 + qt)*512;
  if(lg == 0){
    #pragma unroll
    for(int f=0; f<2; ++f){
      const int ql = wv*32 + f*16 + l15;
      ml[ql*2]     = m_r[f];
      ml[ql*2 + 1] = l_r[f];
    }
  }
}

__global__ void pam_merge_k(const u16* __restrict__ OP, const float* __restrict__ ML,
                            const u16* __restrict__ feat1, const float* __restrict__ gpam,
                            u16* __restrict__ pam)
{
  const int idx = blockIdx.x*256 + threadIdx.x;
  const int ch = idx & 127, qg = idx >> 7;
  const int b = qg >> 12, qq = qg & 4095;
  const int qt = qq >> 8, ql = qq & 255;
  const size_t off = ((size_t)(b*16 + qt)*256 + ql)*128 + ch;
  const size_t mloff = (size_t)(b*16 + qt)*512 + ql*2;
  float m[4], l[4];
  #pragma unroll
  for(int s=0; s<4; ++s){
    m[s] = ML[s*ML_SPLIT_STRIDE + mloff];
    l[s] = ML[s*ML_SPLIT_STRIDE + mloff + 1];
  }
  const float M = fmaxf(fmaxf(m[0],m[1]), fmaxf(m[2],m[3]));
  float num = 0.f, den = 0.f;
  #pragma unroll
  for(int s=0; s<4; ++s){
    const float wgt = __expf(m[s] - M);
    num += wgt * h2f(OP[s*OP_SPLIT_STRIDE + off]);
    den += wgt * l[s];
  }
  pam[idx] = f2h(gpam[0]*num/den + h2f(feat1[idx]));
}

// ---------------- CAM branch (attc + cam) ----------------
__global__ __launch_bounds__(256) void attc_k(const float* __restrict__ enp, u16* __restrict__ attch){
  const int row = blockIdx.x*4 + (threadIdx.x >> 6);
  const int lane = threadIdx.x & 63;
  float e0 = 0.f, e1 = 0.f;
  const int b = row >> 7, c = row & 127;
  #pragma unroll
  for(int s=0; s<16; ++s){
    const float* base = enp + (size_t)(s*4 + b)*128*128 + (size_t)c*128;
    e0 += base[lane];
    e1 += base[64 + lane];
  }
  float mn = fminf(e0, e1);
  #pragma unroll
  for(int d2=1; d2<64; d2<<=1) mn = fminf(mn, __shfl_xor(mn, d2));
  const float p0 = __expf(mn - e0), p1 = __expf(mn - e1);
  float s = p0 + p1;
  #pragma unroll
  for(int d2=1; d2<64; d2<<=1) s += __shfl_xor(s, d2);
  const float rs = 1.f / s;
  attch[(size_t)row*128 + lane]      = f2h(p0*rs);
  attch[(size_t)row*128 + 64 + lane] = f2h(p1*rs);
}

__global__ __launch_bounds__(256) void cam_mfma_k(
    const u16* __restrict__ f2, const u16* __restrict__ attch,
    const float* __restrict__ gcam, u16* __restrict__ cam)
{
  const int b = blockIdx.x >> 5, pt = blockIdx.x & 31;
  const int tid = threadIdx.x;
  const int lane = tid & 63;
  const int wid = tid >> 6;
  const int wr = wid >> 1, wc = wid & 1;
  const int l15 = lane & 15;
  const int lg = lane >> 4;

  f32x4 acc[4][4];
  #pragma unroll
  for(int i=0;i<4;++i)
    #pragma unroll
    for(int j=0;j<4;++j){ f32x4 z = {0.f,0.f,0.f,0.f}; acc[i][j] = z; }

  #pragma unroll
  for(int k0=0; k0<128; k0+=32){
    f16x8 af[4], bf[4];
    #pragma unroll
    for(int ms=0; ms<4; ++ms)
      af[ms] = *(const f16x8*)(f2 + (size_t)(b*4096 + pt*128 + wr*64 + ms*16 + l15)*128 + k0 + lg*8);
    #pragma unroll
    for(int ns=0; ns<4; ++ns)
      bf[ns] = *(const f16x8*)(attch + (size_t)(b*128 + wc*64 + ns*16 + l15)*128 + k0 + lg*8);
    #pragma unroll
    for(int ms=0; ms<4; ++ms)
      #pragma unroll
      for(int ns=0; ns<4; ++ns)
        acc[ms][ns] = MFMA(af[ms], bf[ns], acc[ms][ns]);
  }
  const float g = gcam[0];
  #pragma unroll
  for(int ms=0; ms<4; ++ms)
    #pragma unroll
    for(int ns=0; ns<4; ++ns){
      const int col = wc*64 + ns*16 + l15;
      #pragma unroll
      for(int r=0; r<4; ++r){
        const int p = pt*128 + wr*64 + ms*16 + lg*4 + r;
        const size_t off = (size_t)(b*4096 + p)*128 + col;
        cam[off] = f2h(g*acc[ms][ns][r] + h2f(f2[off]));
      }
    }
}

// ---------------- fusion conv1x1 -> out ----------------
__global__ void final_k(const u16* __restrict__ sa, const u16* __restrict__ sc,
                        const u16* __restrict__ w8t, float* __restrict__ out){
  const int idx = blockIdx.x*256 + threadIdx.x;
  if(idx >= 16384*19) return;
  const int p = idx / 19, n = idx - p*19;
  const u16* ra = sa + (size_t)p*128;
  const u16* rb = sc + (size_t)p*128;
  const u16* wr = w8t + (size_t)n*128;
  float acc = 0.f;
  #pragma unroll
  for(int k=0; k<128; k+=8){
    const uint4 a = *(const uint4*)(ra+k);
    const uint4 b = *(const uint4*)(rb+k);
    const uint4 w = *(const uint4*)(wr+k);
    acc += (hlo(a.x)+hlo(b.x))*hlo(w.x) + (hhi(a.x)+hhi(b.x))*hhi(w.x);
    acc += (hlo(a.y)+hlo(b.y))*hlo(w.y) + (hhi(a.y)+hhi(b.y))*hhi(w.y);
    acc += (hlo(a.z)+hlo(b.z))*hlo(w.z) + (hhi(a.z)+hhi(b.z))*hhi(w.z);
    acc += (hlo(a.w)+hlo(b.w))*hlo(w.w) + (hhi(a.w)+hhi(b.w))*hhi(w.w);
  }
  out[idx] = acc;
}

// ---------------- launch ----------------
extern "C" void kernel_launch(void* const* d_in, const int* in_sizes, int n_in,
                              void* d_out, int out_size, void* d_ws, size_t ws_size,
                              hipStream_t stream)
{
  const float* x    = (const float*)d_in[0];
  const float* w5a  = (const float*)d_in[1];
  const float* bn1g = (const float*)d_in[2];
  const float* bn1b = (const float*)d_in[3];
  const float* bn1m = (const float*)d_in[4];
  const float* bn1v = (const float*)d_in[5];
  const float* wq   = (const float*)d_in[6];
  const float* bq   = (const float*)d_in[7];
  const float* wk   = (const float*)d_in[8];
  const float* bk   = (const float*)d_in[9];
  const float* wv   = (const float*)d_in[10];
  const float* bv   = (const float*)d_in[11];
  const float* gpam = (const float*)d_in[12];
  const float* w5c  = (const float*)d_in[13];
  const float* bn2g = (const float*)d_in[14];
  const float* bn2b = (const float*)d_in[15];
  const float* bn2m = (const float*)d_in[16];
  const float* bn2v = (const float*)d_in[17];
  const float* gcam = (const float*)d_in[18];
  const float* w51  = (const float*)d_in[19];
  const float* bn3g = (const float*)d_in[20];
  const float* bn3b = (const float*)d_in[21];
  const float* bn3m = (const float*)d_in[22];
  const float* bn3v = (const float*)d_in[23];
  const float* w52  = (const float*)d_in[24];
  const float* bn4g = (const float*)d_in[25];
  const float* bn4b = (const float*)d_in[26];
  const float* bn4m = (const float*)d_in[27];
  const float* bn4v = (const float*)d_in[28];
  const float* w8   = (const float*)d_in[29];

  char* ws = (char*)d_ws;
  u16*   XB    = (u16*)(ws + O_XB);
  u16*   FEAT1 = (u16*)(ws + O_F1);
  u16*   F2H   = (u16*)(ws + O_F2H);
  u16*   F2TH  = (u16*)(ws + O_F2TH);
  float* ENP   = (float*)(ws + O_ENP);
  u16*   Q     = (u16*)(ws + O_Q);
  u16*   KM    = (u16*)(ws + O_K);
  u16*   VT    = (u16*)(ws + O_VT);
  u16*   PAM   = (u16*)(ws + O_PAM);
  u16*   CAM   = (u16*)(ws + O_CAM);
  u16*   ATTCH = (u16*)(ws + O_ATTC);
  u16*   OP    = (u16*)(ws + O_OP);
  float* ML    = (float*)(ws + O_ML);
  u16*   W5AT  = (u16*)(ws + O_W5AT);
  u16*   W5CT  = (u16*)(ws + O_W5CT);
  u16*   W51T  = (u16*)(ws + O_W51T);
  u16*   W52T  = (u16*)(ws + O_W52T);
  u16*   WQT   = (u16*)(ws + O_WQT);
  u16*   WKT   = (u16*)(ws + O_WKT);
  u16*   WVT   = (u16*)(ws + O_WVT);
  u16*   W8T   = (u16*)(ws + O_W8T);
  float* B1    = (float*)(ws + O_B1);
  float* B2    = (float*)(ws + O_B2);
  float* B3    = (float*)(ws + O_B3);
  float* B4    = (float*)(ws + O_B4);
  u16*   SA    = (u16*)(ws + O_SA);
  u16*   SC    = (u16*)(ws + O_SC);
  float* OUT   = (float*)d_out;

  prep_all_k<<<14042,256,0,stream>>>(x, XB,
      w5a, bn1g,bn1b,bn1m,bn1v, W5AT, B1,
      w5c, bn2g,bn2b,bn2m,bn2v, W5CT, B2,
      w51, bn3g,bn3b,bn3m,bn3v, W51T, B3,
      w52, bn4g,bn4b,bn4m,bn4v, W52T, B4,
      wq, WQT, wk, WKT, wv, WVT, w8, W8T);

  // feat1 (f16) and feat2 (f16 row-major + f16 transposed) in one launch
  conv3x3_k<512><<<256,512,0,stream>>>(XB, W5AT, B1, FEAT1, nullptr,
                                       XB, W5CT, B2, F2H, F2TH);

  // energy | v_proj | qk_proj fused (all depend only on conv1 outputs)
  mid_fused_k<<<1216,256,0,stream>>>(F2TH, ENP,
                                     FEAT1, WVT, bv, VT,
                                     WQT, bq, WKT, bk, Q, KM);

  attc_k<<<128,256,0,stream>>>(ENP, ATTCH);
  cam_mfma_k<<<128,256,0,stream>>>(F2H, ATTCH, gcam, CAM);

  // PAM: 4-way split-K flash v4 + merge (OP in dead XB region)
  pam_part_k<<<dim3(16,4,4),512,0,stream>>>(Q, KM, VT, OP, ML);
  pam_merge_k<<<8192,256,0,stream>>>(OP, ML, FEAT1, gpam, PAM);

  // sa_conv (from pam) and sc_conv (from cam) in one launch; SA/SC alias XB
  conv3x3_k<128><<<256,512,0,stream>>>(PAM, W51T, B3, SA, nullptr,
                                       CAM, W52T, B4, SC, nullptr);

  final_k<<<1216,256,0,stream>>>(SA, SC, W8T, OUT);
}